// Round 5
// baseline (909.443 us; speedup 1.0000x reference)
//
#include <hip/hip_runtime.h>
#include <hip/hip_bf16.h>
#include <stdint.h>

#define N_TOK 8192
#define CDIM  1024
#define HDIM  4096
#define NEXP  8
#define BM    256
#define BN    256
#define BKK   64

typedef __attribute__((ext_vector_type(8))) short bf16x8;
typedef __attribute__((ext_vector_type(4))) float f32x4;

static __device__ __forceinline__ uint16_t f2bf(float f) {
  union { float f; uint32_t u; } v; v.f = f;
  uint32_t r = v.u + 0x7FFF + ((v.u >> 16) & 1);
  return (uint16_t)(r >> 16);
}

__device__ __forceinline__ void gload_lds16(const void* g, void* l) {
  __builtin_amdgcn_global_load_lds(
      (const __attribute__((address_space(1))) uint32_t*)g,
      (__attribute__((address_space(3))) uint32_t*)l, 16, 0, 0);
}

// ------- transpose+convert: src [R][S] f32 -> dst [S][R] bf16; 128(r)x64(c) tile -------
// LDS float tile with slot^=(row>>3)&15 XOR swizzle: store 2-way, col-read 2-way (both free).
__global__ void transcvt_kernel(const float* __restrict__ src, uint16_t* __restrict__ dst,
                                int R, int S) {
  __shared__ float tile[128 * 64];
  size_t base = (size_t)blockIdx.z * (size_t)R * S;
  int c0 = blockIdx.x * 64, r0 = blockIdx.y * 128;
  int t = threadIdx.x;
#pragma unroll
  for (int q = 0; q < 8; q++) {
    int idx = q * 256 + t;
    int row = idx >> 4, s = idx & 15;
    float4 v = *(const float4*)&src[base + (size_t)(r0 + row) * S + c0 + s * 4];
    *(float4*)&tile[row * 64 + ((s ^ ((row >> 3) & 15)) << 2)] = v;
  }
  __syncthreads();
#pragma unroll
  for (int q = 0; q < 4; q++) {
    int idx = q * 256 + t;
    int crow = idx >> 4, r8 = (idx & 15) * 8;
    bf16x8 o;
#pragma unroll
    for (int k = 0; k < 8; k++) {
      int r = r8 + k;
      o[k] = (short)f2bf(tile[r * 64 + (((crow >> 2) ^ ((r >> 3) & 15)) << 2) + (crow & 3)]);
    }
    *(bf16x8*)&dst[base + (size_t)(c0 + crow) * R + r0 + r8] = o;
  }
}

// ---------------- router (+ fused x->bf16): one wave per token ----------------
__global__ void router_kernel(const float* __restrict__ x, const float* __restrict__ Wr,
                              int* __restrict__ cnt, int* __restrict__ te,
                              float* __restrict__ tw, uint16_t* __restrict__ xb) {
  int wid = (blockIdx.x * blockDim.x + threadIdx.x) >> 6;
  int lane = threadIdx.x & 63;
  if (wid >= N_TOK) return;
  const float* xr = x + (size_t)wid * CDIM;
  uint16_t* xbr = xb + (size_t)wid * CDIM;
  float p[NEXP];
#pragma unroll
  for (int e = 0; e < NEXP; e++) p[e] = 0.f;
  for (int kk = 0; kk < CDIM / 64; kk++) {
    float xv = xr[kk * 64 + lane];
    xbr[kk * 64 + lane] = f2bf(xv);
#pragma unroll
    for (int e = 0; e < NEXP; e++)
      p[e] += xv * Wr[e * CDIM + kk * 64 + lane];
  }
#pragma unroll
  for (int e = 0; e < NEXP; e++) {
    float v = p[e];
#pragma unroll
    for (int s = 32; s > 0; s >>= 1) v += __shfl_xor(v, s);
    p[e] = v;
  }
  if (lane == 0) {
    float m0 = -1e30f, m1 = -1e30f; int i0 = 0, i1 = 0;
#pragma unroll
    for (int e = 0; e < NEXP; e++) {
      float v = p[e];
      if (v > m0) { m1 = m0; i1 = i0; m0 = v; i0 = e; }
      else if (v > m1) { m1 = v; i1 = e; }
    }
    float w0 = 1.f / (1.f + __expf(m1 - m0));
    te[wid] = i0 | (i1 << 16);
    tw[wid] = w0;
    atomicAdd(&cnt[i0], 1);
    atomicAdd(&cnt[i1], 1);
  }
}

__global__ void prefix_kernel(const int* __restrict__ cnt, int* __restrict__ offs,
                              int* __restrict__ fill) {
  if (threadIdx.x == 0) {
    int acc = 0;
    for (int e = 0; e < NEXP; e++) { offs[e] = acc; fill[e] = acc; acc += cnt[e]; }
    offs[NEXP] = acc;
  }
}

__global__ void bucket_kernel(const int* __restrict__ te, const float* __restrict__ tw,
                              int* __restrict__ fill, int* __restrict__ perm,
                              float* __restrict__ pw) {
  int t = blockIdx.x * 256 + threadIdx.x;
  if (t >= N_TOK) return;
  int e01 = te[t];
  int e0 = e01 & 0xffff, e1 = e01 >> 16;
  float w0 = tw[t];
  int p0 = atomicAdd(&fill[e0], 1);
  perm[p0] = t; pw[p0] = w0;
  int p1 = atomicAdd(&fill[e1], 1);
  perm[p1] = t; pw[p1] = 1.f - w0;
}

// ---- grouped GEMM: 256x256, BK=64, 8 waves (2Mx4N, wave tile 128x64), 2 LDS bufs,
// ---- m201-faithful 8-phase / 2-K-tile schedule: half-tile staging (2 loads/phase) into
// ---- just-freed slots, counted vmcnt(4) once per K-tile (ph4/ph8), XOR-swizzled (0-conflict).
template<bool GATHER, bool RELU2, int NDIM, int KDIM>
__global__ __launch_bounds__(512, 2)
void moe_gemm(const uint16_t* __restrict__ A, const uint16_t* __restrict__ Bt,
              const int* __restrict__ offs, const int* __restrict__ perm,
              const float* __restrict__ pw, uint16_t* __restrict__ hb,
              float* __restrict__ out) {
  const int NB = NDIM / BN;
  const int RBMAX = 2 * N_TOK / BM;    // 64
  int nwg = gridDim.x;
  int bid = blockIdx.x;
  int wid = (bid & 7) * (nwg >> 3) + (bid >> 3);  // chunked XCD swizzle (bijective)
  int rb_i = wid % RBMAX;
  int rest = wid / RBMAX;
  int nb = rest % NB;
  int e  = rest / NB;
  int o0 = offs[e];
  int Me = offs[e + 1] - o0;
  int rb = rb_i * BM;
  if (rb >= Me) return;
  int nb0 = nb * BN;

  __shared__ uint16_t smA[2][BM * BKK];   // 2 x 32KB
  __shared__ uint16_t smB[2][BN * BKK];   // 2 x 32KB  (128KB)

  int tid = threadIdx.x;
  int w = tid >> 6, l = tid & 63;
  int wr = w >> 2, wc = w & 3;            // wave tile rows [wr*128,+128), cols [wc*64,+64)
  int cl = l & 15;
  int kh = l >> 4;

  // staging pointers: chunk c = j*512+tid -> row = c>>3 (64 rows per j), slot = c&7;
  // global k-chunk = slot ^ (row&7)  (XOR swizzle folded into source, linear LDS dest)
  const uint16_t* aptr[4];
#pragma unroll
  for (int j = 0; j < 4; j++) {
    int c = j * 512 + tid;
    int row = c >> 3, slot = c & 7;
    int gi = o0 + rb + row;
    if (gi > 2 * N_TOK - 1) gi = 2 * N_TOK - 1;
    int arow = GATHER ? perm[gi] : gi;
    aptr[j] = A + (size_t)arow * KDIM + ((slot ^ (row & 7)) << 3);
  }
  const uint16_t* bbase = Bt + (size_t)e * NDIM * KDIM;
  const uint16_t* bptr[4];
#pragma unroll
  for (int j = 0; j < 4; j++) {
    int c = j * 512 + tid;
    int row = c >> 3, slot = c & 7;
    bptr[j] = bbase + (size_t)(nb0 + row) * KDIM + ((slot ^ (row & 7)) << 3);
  }

  f32x4 acc[8][4];
#pragma unroll
  for (int m = 0; m < 8; m++)
#pragma unroll
    for (int n = 0; n < 4; n++)
      acc[m][n] = (f32x4)0.f;

  // stage one half-tile (2 loads/thread): half 0 -> rows 0..127 (j=0,1), half 1 -> j=2,3
#define SG_A(buf, half, kt) do {                                                       \
    gload_lds16(aptr[2*(half)]   + (kt) * BKK, (char*)&smA[buf][0] + (2*(half))   * 8192 + tid * 16); \
    gload_lds16(aptr[2*(half)+1] + (kt) * BKK, (char*)&smA[buf][0] + (2*(half)+1) * 8192 + tid * 16); \
  } while (0)
#define SG_B(buf, half, kt) do {                                                       \
    gload_lds16(bptr[2*(half)]   + (kt) * BKK, (char*)&smB[buf][0] + (2*(half))   * 8192 + tid * 16); \
    gload_lds16(bptr[2*(half)+1] + (kt) * BKK, (char*)&smB[buf][0] + (2*(half)+1) * 8192 + tid * 16); \
  } while (0)

#define LDSF(base, row, s) (*(const bf16x8*)&(base)[(row) * BKK + (((s) ^ ((row) & 7)) << 3)])

#define BAR_PRE() do {                                         \
    asm volatile("s_barrier" ::: "memory");                    \
    asm volatile("s_waitcnt lgkmcnt(0)" ::: "memory");         \
    __builtin_amdgcn_sched_barrier(0); } while (0)
#define BAR_POST() asm volatile("s_barrier" ::: "memory")

  const int NT = KDIM / BKK;
  const int NIT = NT / 2;

  // prologue: A0,B0 -> buf0; B1 -> buf1 (12 loads); wait all but B1 (4)
  SG_A(0, 0, 0); SG_A(0, 1, 0);
  SG_B(0, 0, 0); SG_B(0, 1, 0);
  SG_B(1, 0, 1); SG_B(1, 1, 1);
  asm volatile("s_waitcnt vmcnt(4)" ::: "memory");
  __builtin_amdgcn_sched_barrier(0);
  asm volatile("s_barrier" ::: "memory");

  bf16x8 aF[4][2], b01[2][2], b23[2][2];
  const uint16_t* sA0 = &smA[0][0]; const uint16_t* sB0 = &smB[0][0];
  const uint16_t* sA1 = &smA[1][0]; const uint16_t* sB1 = &smB[1][0];

  for (int j = 0; j < NIT; ++j) {
    bool pf = (j + 1 < NIT);
    int t1 = 2 * j + 1, t2 = 2 * j + 2, t3 = 2 * j + 3;

    // ---------- K-tile T0 = 2j (buf0) ----------
    // ph1: read aF-lo band + b01 ; stage A(t1)-lo -> buf1
#pragma unroll
    for (int m = 0; m < 4; m++)
#pragma unroll
      for (int kk = 0; kk < 2; kk++)
        aF[m][kk] = LDSF(sA0, wr * 128 + m * 16 + cl, kk * 4 + kh);
#pragma unroll
    for (int n = 0; n < 2; n++)
#pragma unroll
      for (int kk = 0; kk < 2; kk++)
        b01[n][kk] = LDSF(sB0, wc * 64 + n * 16 + cl, kk * 4 + kh);
    SG_A(1, 0, t1);
    BAR_PRE();
    __builtin_amdgcn_s_setprio(1);
#pragma unroll
    for (int m = 0; m < 4; m++)
#pragma unroll
      for (int n = 0; n < 2; n++) {
        acc[m][n] = __builtin_amdgcn_mfma_f32_16x16x32_bf16(aF[m][0], b01[n][0], acc[m][n], 0, 0, 0);
        acc[m][n] = __builtin_amdgcn_mfma_f32_16x16x32_bf16(aF[m][1], b01[n][1], acc[m][n], 0, 0, 0);
      }
    __builtin_amdgcn_s_setprio(0);
    BAR_POST();
    // ph2: read b23 ; stage A(t1)-hi -> buf1
#pragma unroll
    for (int n = 0; n < 2; n++)
#pragma unroll
      for (int kk = 0; kk < 2; kk++)
        b23[n][kk] = LDSF(sB0, wc * 64 + (n + 2) * 16 + cl, kk * 4 + kh);
    SG_A(1, 1, t1);
    BAR_PRE();
    __builtin_amdgcn_s_setprio(1);
#pragma unroll
    for (int m = 0; m < 4; m++)
#pragma unroll
      for (int n = 0; n < 2; n++) {
        acc[m][n + 2] = __builtin_amdgcn_mfma_f32_16x16x32_bf16(aF[m][0], b23[n][0], acc[m][n + 2], 0, 0, 0);
        acc[m][n + 2] = __builtin_amdgcn_mfma_f32_16x16x32_bf16(aF[m][1], b23[n][1], acc[m][n + 2], 0, 0, 0);
      }
    __builtin_amdgcn_s_setprio(0);
    BAR_POST();
    // ph3: read aF-hi band ; stage B(t2)-lo -> buf0 (B slots freed after ph2)
#pragma unroll
    for (int m = 0; m < 4; m++)
#pragma unroll
      for (int kk = 0; kk < 2; kk++)
        aF[m][kk] = LDSF(sA0, wr * 128 + 64 + m * 16 + cl, kk * 4 + kh);
    if (pf) SG_B(0, 0, t2);
    BAR_PRE();
    __builtin_amdgcn_s_setprio(1);
#pragma unroll
    for (int m = 0; m < 4; m++)
#pragma unroll
      for (int n = 0; n < 2; n++) {
        acc[m + 4][n + 2] = __builtin_amdgcn_mfma_f32_16x16x32_bf16(aF[m][0], b23[n][0], acc[m + 4][n + 2], 0, 0, 0);
        acc[m + 4][n + 2] = __builtin_amdgcn_mfma_f32_16x16x32_bf16(aF[m][1], b23[n][1], acc[m + 4][n + 2], 0, 0, 0);
      }
    __builtin_amdgcn_s_setprio(0);
    BAR_POST();
    // ph4: stage B(t2)-hi ; counted vmcnt (guards buf1 tile t1 for ph5) ; MFMA with held b01
    if (pf) SG_B(0, 1, t2);
    if (pf) { asm volatile("s_waitcnt vmcnt(4)" ::: "memory"); }
    else    { asm volatile("s_waitcnt vmcnt(0)" ::: "memory"); }
    __builtin_amdgcn_sched_barrier(0);
    BAR_PRE();
    __builtin_amdgcn_s_setprio(1);
#pragma unroll
    for (int m = 0; m < 4; m++)
#pragma unroll
      for (int n = 0; n < 2; n++) {
        acc[m + 4][n] = __builtin_amdgcn_mfma_f32_16x16x32_bf16(aF[m][0], b01[n][0], acc[m + 4][n], 0, 0, 0);
        acc[m + 4][n] = __builtin_amdgcn_mfma_f32_16x16x32_bf16(aF[m][1], b01[n][1], acc[m + 4][n], 0, 0, 0);
      }
    __builtin_amdgcn_s_setprio(0);
    BAR_POST();

    // ---------- K-tile T1 = 2j+1 (buf1) ----------
    // ph5: read aF-lo + b01 ; stage A(t2)-lo -> buf0 (A slots freed after ph3)
#pragma unroll
    for (int m = 0; m < 4; m++)
#pragma unroll
      for (int kk = 0; kk < 2; kk++)
        aF[m][kk] = LDSF(sA1, wr * 128 + m * 16 + cl, kk * 4 + kh);
#pragma unroll
    for (int n = 0; n < 2; n++)
#pragma unroll
      for (int kk = 0; kk < 2; kk++)
        b01[n][kk] = LDSF(sB1, wc * 64 + n * 16 + cl, kk * 4 + kh);
    if (pf) SG_A(0, 0, t2);
    BAR_PRE();
    __builtin_amdgcn_s_setprio(1);
#pragma unroll
    for (int m = 0; m < 4; m++)
#pragma unroll
      for (int n = 0; n < 2; n++) {
        acc[m][n] = __builtin_amdgcn_mfma_f32_16x16x32_bf16(aF[m][0], b01[n][0], acc[m][n], 0, 0, 0);
        acc[m][n] = __builtin_amdgcn_mfma_f32_16x16x32_bf16(aF[m][1], b01[n][1], acc[m][n], 0, 0, 0);
      }
    __builtin_amdgcn_s_setprio(0);
    BAR_POST();
    // ph6: read b23 ; stage A(t2)-hi -> buf0
#pragma unroll
    for (int n = 0; n < 2; n++)
#pragma unroll
      for (int kk = 0; kk < 2; kk++)
        b23[n][kk] = LDSF(sB1, wc * 64 + (n + 2) * 16 + cl, kk * 4 + kh);
    if (pf) SG_A(0, 1, t2);
    BAR_PRE();
    __builtin_amdgcn_s_setprio(1);
#pragma unroll
    for (int m = 0; m < 4; m++)
#pragma unroll
      for (int n = 0; n < 2; n++) {
        acc[m][n + 2] = __builtin_amdgcn_mfma_f32_16x16x32_bf16(aF[m][0], b23[n][0], acc[m][n + 2], 0, 0, 0);
        acc[m][n + 2] = __builtin_amdgcn_mfma_f32_16x16x32_bf16(aF[m][1], b23[n][1], acc[m][n + 2], 0, 0, 0);
      }
    __builtin_amdgcn_s_setprio(0);
    BAR_POST();
    // ph7: read aF-hi ; stage B(t3)-lo -> buf1
#pragma unroll
    for (int m = 0; m < 4; m++)
#pragma unroll
      for (int kk = 0; kk < 2; kk++)
        aF[m][kk] = LDSF(sA1, wr * 128 + 64 + m * 16 + cl, kk * 4 + kh);
    if (pf) SG_B(1, 0, t3);
    BAR_PRE();
    __builtin_amdgcn_s_setprio(1);
#pragma unroll
    for (int m = 0; m < 4; m++)
#pragma unroll
      for (int n = 0; n < 2; n++) {
        acc[m + 4][n + 2] = __builtin_amdgcn_mfma_f32_16x16x32_bf16(aF[m][0], b23[n][0], acc[m + 4][n + 2], 0, 0, 0);
        acc[m + 4][n + 2] = __builtin_amdgcn_mfma_f32_16x16x32_bf16(aF[m][1], b23[n][1], acc[m + 4][n + 2], 0, 0, 0);
      }
    __builtin_amdgcn_s_setprio(0);
    BAR_POST();
    // ph8: stage B(t3)-hi ; counted vmcnt (guards buf0 tile t2 for next ph1) ; MFMA held b01
    if (pf) {
      SG_B(1, 1, t3);
      asm volatile("s_waitcnt vmcnt(4)" ::: "memory");
      __builtin_amdgcn_sched_barrier(0);
    }
    BAR_PRE();
    __builtin_amdgcn_s_setprio(1);
#pragma unroll
    for (int m = 0; m < 4; m++)
#pragma unroll
      for (int n = 0; n < 2; n++) {
        acc[m + 4][n] = __builtin_amdgcn_mfma_f32_16x16x32_bf16(aF[m][0], b01[n][0], acc[m + 4][n], 0, 0, 0);
        acc[m + 4][n] = __builtin_amdgcn_mfma_f32_16x16x32_bf16(aF[m][1], b01[n][1], acc[m + 4][n], 0, 0, 0);
      }
    __builtin_amdgcn_s_setprio(0);
    BAR_POST();
  }
#undef SG_A
#undef SG_B
#undef LDSF
#undef BAR_PRE
#undef BAR_POST

  int rg = (l >> 4) * 4;
  if (RELU2) {
#pragma unroll
    for (int m = 0; m < 8; m++) {
#pragma unroll
      for (int jj = 0; jj < 4; jj++) {
        int er = rb + wr * 128 + m * 16 + rg + jj;
        if (er < Me) {
          size_t rowoff = (size_t)(o0 + er) * NDIM;
#pragma unroll
          for (int n = 0; n < 4; n++) {
            int gc = nb0 + wc * 64 + n * 16 + cl;
            float v = acc[m][n][jj];
            v = v > 0.f ? v * v : 0.f;
            hb[rowoff + gc] = f2bf(v);
          }
        }
      }
    }
  } else {
#pragma unroll
    for (int m = 0; m < 8; m++) {
#pragma unroll
      for (int jj = 0; jj < 4; jj++) {
        int er = rb + wr * 128 + m * 16 + rg + jj;
        if (er < Me) {
          int gi = o0 + er;
          int tok = perm[gi];
          float wgt = pw[gi];
          size_t rowoff = (size_t)tok * NDIM;
#pragma unroll
          for (int n = 0; n < 4; n++) {
            int gc = nb0 + wc * 64 + n * 16 + cl;
            atomicAdd(&out[rowoff + gc], wgt * acc[m][n][jj]);
          }
        }
      }
    }
  }
}

extern "C" void kernel_launch(void* const* d_in, const int* in_sizes, int n_in,
                              void* d_out, int out_size, void* d_ws, size_t ws_size,
                              hipStream_t stream) {
  const float* x  = (const float*)d_in[0];
  const float* Wr = (const float*)d_in[1];
  const float* W1 = (const float*)d_in[2];
  const float* W2 = (const float*)d_in[3];
  float* out = (float*)d_out;

  char* ws = (char*)d_ws;
  size_t off = 0;
  uint16_t* xb  = (uint16_t*)(ws + off); off += (size_t)N_TOK * CDIM * 2;
  uint16_t* W1t = (uint16_t*)(ws + off); off += (size_t)NEXP * CDIM * HDIM * 2;
  uint16_t* W2t = (uint16_t*)(ws + off); off += (size_t)NEXP * CDIM * HDIM * 2;
  uint16_t* hb  = (uint16_t*)(ws + off); off += (size_t)2 * N_TOK * HDIM * 2;
  int*   perm = (int*)(ws + off); off += (size_t)2 * N_TOK * 4;
  float* pwt  = (float*)(ws + off); off += (size_t)2 * N_TOK * 4;
  int*   te   = (int*)(ws + off); off += (size_t)N_TOK * 4;
  float* tw   = (float*)(ws + off); off += (size_t)N_TOK * 4;
  int*   cnt  = (int*)(ws + off); off += 16 * 4;
  int*   offs = (int*)(ws + off); off += 16 * 4;
  int*   fill = (int*)(ws + off); off += 16 * 4;

  hipMemsetAsync(d_out, 0, (size_t)out_size * sizeof(float), stream);
  hipMemsetAsync(cnt, 0, 16 * 4, stream);

  router_kernel<<<N_TOK / 4, 256, 0, stream>>>(x, Wr, cnt, te, tw, xb);
  transcvt_kernel<<<dim3(HDIM / 64, CDIM / 128, NEXP), 256, 0, stream>>>(W1, W1t, CDIM, HDIM);
  transcvt_kernel<<<dim3(CDIM / 64, HDIM / 128, NEXP), 256, 0, stream>>>(W2, W2t, HDIM, CDIM);
  prefix_kernel<<<1, 64, 0, stream>>>(cnt, offs, fill);
  bucket_kernel<<<N_TOK / 256, 256, 0, stream>>>(te, tw, fill, perm, pwt);

  // GEMM1: h = relu^2(x @ W1)  [rows gathered via perm]  N=4096, K=1024
  moe_gemm<true, true, HDIM, CDIM>
      <<<(2 * N_TOK / BM) * (HDIM / BN) * NEXP, 512, 0, stream>>>(
      xb, W1t, offs, perm, pwt, hb, out);
  // GEMM2: out += gate * (h @ W2)   N=1024, K=4096
  moe_gemm<false, false, CDIM, HDIM>
      <<<(2 * N_TOK / BM) * (CDIM / BN) * NEXP, 512, 0, stream>>>(
      hb, W2t, offs, perm, pwt, hb, out);
}